// Round 2
// baseline (120.631 us; speedup 1.0000x reference)
//
#include <hip/hip_runtime.h>
#include <math.h>

#define BB 4
#define NN 512
#define FIN 256
#define NH 8
#define FD 32
#define HF 256               // NH * FD
// leaky(x) = max(x, 0.21x) = CA*x + CB*|x|, pre-scaled by log2(e) so the
// softmax numerator is p = exp2(e) (saves the v_mul __expf emits).
#define CA 0.8728305f        // 0.605 * log2(e)
#define CB 0.5698645f        // 0.395 * log2(e)
#define IT 32                // i-tile rows; grid 512 = 2 blocks/CU
#define ESTR 268             // uints/e_s row: 1072B, 16B-aligned
#define GTS 260              // grT row stride in uints (16B-aligned)
// phase-1 wave holds 4 jg groups: XOR swizzle spreads their banks;
// permutation within 8-blocks so staging writes stay conflict-free
#define GLX(j) ((j) ^ (((j) >> 5) & 7))
#define ALX(j) ((j) + ((j) >> 5))

typedef _Float16 h2_t __attribute__((ext_vector_type(2)));
union H2U { unsigned u; h2_t h; };
typedef __fp16 v8h __attribute__((ext_vector_type(8)));  // MFMA a/b frag
typedef float v4f __attribute__((ext_vector_type(4)));   // MFMA acc
union U8 { uint4 u4; v8h h; };

__device__ __forceinline__ h2_t pkrtz(float a, float b) {
  auto r = __builtin_amdgcn_cvt_pkrtz(a, b);
  union { decltype(r) f; h2_t h; } u;
  u.f = r;
  return u.h;
}
__device__ __forceinline__ unsigned pkrtz_u(float a, float b) {
  H2U u; u.h = pkrtz(a, b);
  return u.u;
}

// x = g2 + q2 (v_pk_add_f16); |x| (v_and 0x7fff7fff); acc += u2.|x| (v_dot2)
__device__ __forceinline__ float acc2(unsigned g, h2_t q, h2_t u, float acc) {
  H2U v; v.u = g;
  h2_t s = v.h + q;
  H2U a; a.h = s; a.u &= 0x7fff7fffu;
  return __builtin_amdgcn_fdot2(a.h, u, acc, false);
}

// 32-feature score for one j from 4 uint4 (8 fp16 each)
__device__ __forceinline__ float score16(uint4 g0, uint4 g1, uint4 g2, uint4 g3,
                                         const h2_t* qh, const h2_t* uh,
                                         float init) {
  float e0 = init, e1 = 0.f;
  e0 = acc2(g0.x, qh[0], uh[0], e0);
  e1 = acc2(g0.y, qh[1], uh[1], e1);
  e0 = acc2(g0.z, qh[2], uh[2], e0);
  e1 = acc2(g0.w, qh[3], uh[3], e1);
  e0 = acc2(g1.x, qh[4], uh[4], e0);
  e1 = acc2(g1.y, qh[5], uh[5], e1);
  e0 = acc2(g1.z, qh[6], uh[6], e0);
  e1 = acc2(g1.w, qh[7], uh[7], e1);
  e0 = acc2(g2.x, qh[8], uh[8], e0);
  e1 = acc2(g2.y, qh[9], uh[9], e1);
  e0 = acc2(g2.z, qh[10], uh[10], e0);
  e1 = acc2(g2.w, qh[11], uh[11], e1);
  e0 = acc2(g3.x, qh[12], uh[12], e0);
  e1 = acc2(g3.y, qh[13], uh[13], e1);
  e0 = acc2(g3.z, qh[14], uh[14], e0);
  e1 = acc2(g3.w, qh[15], uh[15], e1);
  return e0 + e1;
}

// ---------------------------------------------------------------------------
// Kernel 1: dual GEMM g = h @ W, both outputs fp16.
// R14: 512-thread blocks, 4 rows/thread (t&255=col, t>>8=row-half).
// Same FLOPs/k-order as R10 (absmax-identical), but 4096 waves -> 4
// waves/SIMD (was 2) and half the redundant h float4 broadcasts per thread,
// so L1/L2 load latency is actually covered.
// ---------------------------------------------------------------------------
__global__ __launch_bounds__(512) void gemm_dual(
    const float* __restrict__ h, const float* __restrict__ Wl,
    const float* __restrict__ Wr, _Float16* __restrict__ glh,
    _Float16* __restrict__ grh) {
  const int t = threadIdx.x;
  const int col = t & 255;
  const int rh = t >> 8;                       // 0/1: row-half
  const int row0 = blockIdx.x * 8 + rh * 4;
  const float* __restrict__ W = blockIdx.y ? Wr : Wl;

  float acc[4] = {0.f, 0.f, 0.f, 0.f};
  const float* Wp = W + col;
  const float* hp = h + (size_t)row0 * FIN;

#pragma unroll 2
  for (int k4 = 0; k4 < FIN / 4; ++k4) {
    float4 hv[4];
#pragma unroll
    for (int r = 0; r < 4; ++r)
      hv[r] = *(const float4*)(hp + r * FIN + 4 * k4);
#pragma unroll
    for (int kk = 0; kk < 4; ++kk) {
      const float w = Wp[(size_t)(4 * k4 + kk) * HF];
#pragma unroll
      for (int r = 0; r < 4; ++r) {
        const float hval = (kk == 0) ? hv[r].x
                         : (kk == 1) ? hv[r].y
                         : (kk == 2) ? hv[r].z : hv[r].w;
        acc[r] = fmaf(hval, w, acc[r]);
      }
    }
  }

  _Float16* gp = (blockIdx.y ? grh : glh) + (size_t)row0 * HF + col;
#pragma unroll
  for (int r = 0; r < 4; ++r) gp[(size_t)r * HF] = (_Float16)acc[r];
}

// ---------------------------------------------------------------------------
// Kernel 2: fused GATv2 attention. Block = (head hh, 32-row i-tile, batch b).
// R13 structure: 512-thread blocks (8 waves, 4/SIMD), 2 rows/thread sharing
// gl reads (r0 = t&15, jg = t>>4 spans 32 groups x 16 j). LDS 72.4 KB ->
// 2 blocks/CU; grid 512 blocks = exactly 2/CU, no tail.
// Softmax without max-pass (shift-invariant; e bounded ~|2|; masked p = 0
// exactly, matching ref's fp32 underflow); log2 domain: p = exp2(e).
// ---------------------------------------------------------------------------
__global__ __launch_bounds__(512, 4) void gat_attn(
    const _Float16* __restrict__ glh, const _Float16* __restrict__ grh,
    const int* __restrict__ adj, const float* __restrict__ aw,
    float* __restrict__ out) {
  __shared__ __align__(16) unsigned ubuf[32 * GTS];  // 33.3 KB gl4/grT union
  __shared__ __align__(16) unsigned e_s[IT][ESTR];   // 34.3 KB fp16 p
  __shared__ float Al_s[544];                        // 2.1 KB, ALX-skewed
  __shared__ float s_part[32][33];                   // 4.2 KB row-sum parts
  __shared__ float inv_l[IT];

  const int t = threadIdx.x;
  const int hh = blockIdx.x;
  const int i0 = blockIdx.y * IT;
  const int b = blockIdx.z;
  const int r0 = t & 15;   // phase-1 rows {r0, r0+16}
  const int jg = t >> 4;   // 0..31, 16 j each

  uint4* gl4 = (uint4*)ubuf;  // [k4*512 + GLX(j)], k-major

  const _Float16* glp = glh + (size_t)b * NN * HF + hh * FD;

  // ---- per-thread prep: aw -> wv/uh; q rows r0 & r0+16 -> qh/qh2 + a_r ----
  h2_t wv[16], uh[16], qh[16], qh2[16];
  float a_r0 = 0.f, a_r1 = 0.f;
  {
#pragma unroll
    for (int f4 = 0; f4 < 8; ++f4) {
      const float4 w4 = *(const float4*)(aw + 4 * f4);
      wv[2 * f4] = pkrtz(CA * w4.x, CA * w4.y);
      wv[2 * f4 + 1] = pkrtz(CA * w4.z, CA * w4.w);
      uh[2 * f4] = pkrtz(CB * w4.x, CB * w4.y);
      uh[2 * f4 + 1] = pkrtz(CB * w4.z, CB * w4.w);
    }
    const uint4* qa =
        (const uint4*)(grh + (size_t)(b * NN + i0 + r0) * HF + hh * FD);
    const uint4* qb =
        (const uint4*)(grh + (size_t)(b * NN + i0 + r0 + 16) * HF + hh * FD);
    const uint4 q0 = qa[0], q1 = qa[1], q2 = qa[2], q3 = qa[3];
    const uint4 p0 = qb[0], p1 = qb[1], p2 = qb[2], p3 = qb[3];
    H2U z;
    z.u = q0.x; qh[0] = z.h;  z.u = q0.y; qh[1] = z.h;
    z.u = q0.z; qh[2] = z.h;  z.u = q0.w; qh[3] = z.h;
    z.u = q1.x; qh[4] = z.h;  z.u = q1.y; qh[5] = z.h;
    z.u = q1.z; qh[6] = z.h;  z.u = q1.w; qh[7] = z.h;
    z.u = q2.x; qh[8] = z.h;  z.u = q2.y; qh[9] = z.h;
    z.u = q2.z; qh[10] = z.h; z.u = q2.w; qh[11] = z.h;
    z.u = q3.x; qh[12] = z.h; z.u = q3.y; qh[13] = z.h;
    z.u = q3.z; qh[14] = z.h; z.u = q3.w; qh[15] = z.h;
    z.u = p0.x; qh2[0] = z.h;  z.u = p0.y; qh2[1] = z.h;
    z.u = p0.z; qh2[2] = z.h;  z.u = p0.w; qh2[3] = z.h;
    z.u = p1.x; qh2[4] = z.h;  z.u = p1.y; qh2[5] = z.h;
    z.u = p1.z; qh2[6] = z.h;  z.u = p1.w; qh2[7] = z.h;
    z.u = p2.x; qh2[8] = z.h;  z.u = p2.y; qh2[9] = z.h;
    z.u = p2.z; qh2[10] = z.h; z.u = p2.w; qh2[11] = z.h;
    z.u = p3.x; qh2[12] = z.h; z.u = p3.y; qh2[13] = z.h;
    z.u = p3.z; qh2[14] = z.h; z.u = p3.w; qh2[15] = z.h;
#pragma unroll
    for (int f2 = 0; f2 < 16; ++f2) {
      a_r0 = __builtin_amdgcn_fdot2(qh[f2], wv[f2], a_r0, false);
      a_r1 = __builtin_amdgcn_fdot2(qh2[f2], wv[f2], a_r1, false);
    }
  }

  // ---- pre-pass: stage gl slice -> LDS (GLX-swizzled) + Al (ALX) ----
  {
    const int j = t;  // 512 threads, one j each
    const uint4* gp = (const uint4*)(glp + (size_t)j * HF);
    const uint4 g0 = gp[0], g1 = gp[1], g2 = gp[2], g3 = gp[3];
    const int jx = GLX(j);
    gl4[0 * NN + jx] = g0;
    gl4[1 * NN + jx] = g1;
    gl4[2 * NN + jx] = g2;
    gl4[3 * NN + jx] = g3;
    float s0 = 0.f, s1 = 0.f;
    H2U v;
#define ALD(gu, i)                                                  \
  v.u = gu.x; s0 = __builtin_amdgcn_fdot2(v.h, wv[i+0], s0, false); \
  v.u = gu.y; s1 = __builtin_amdgcn_fdot2(v.h, wv[i+1], s1, false); \
  v.u = gu.z; s0 = __builtin_amdgcn_fdot2(v.h, wv[i+2], s0, false); \
  v.u = gu.w; s1 = __builtin_amdgcn_fdot2(v.h, wv[i+3], s1, false);
    ALD(g0, 0) ALD(g1, 4) ALD(g2, 8) ALD(g3, 12)
#undef ALD
    Al_s[ALX(j)] = s0 + s1;
  }
  __syncthreads();

  // ---- phase 1: p = exp2(e) for 2 rows x 16 j; local row sums ----
  {
    unsigned* erow0 = &e_s[r0][jg * 8];
    unsigned* erow1 = &e_s[r0 + 16][jg * 8];
    const int* adjp0 = adj + (size_t)(i0 + r0) * NN + jg * 16;
    const int* adjp1 = adj + (size_t)(i0 + r0 + 16) * NN + jg * 16;
    float srow0 = 0.f, srow1 = 0.f;
#pragma unroll 2
    for (int g4 = 0; g4 < 4; ++g4) {
      const int4 m0 = ((const int4*)adjp0)[g4];
      const int4 m1 = ((const int4*)adjp1)[g4];
      float p0[4], p1[4];
#pragma unroll
      for (int k = 0; k < 4; ++k) {
        const int j = jg * 16 + 4 * g4 + k;
        const int jx = GLX(j);
        const uint4 g0 = gl4[0 * NN + jx], g1 = gl4[1 * NN + jx];
        const uint4 g2 = gl4[2 * NN + jx], g3 = gl4[3 * NN + jx];
        const float al = Al_s[ALX(j)];
        const float e0 = score16(g0, g1, g2, g3, qh, uh, al + a_r0);
        const float e1 = score16(g0, g1, g2, g3, qh2, uh, al + a_r1);
        const int mk = (k == 0) ? m0.x : (k == 1) ? m0.y : (k == 2) ? m0.z : m0.w;
        const int nk = (k == 0) ? m1.x : (k == 1) ? m1.y : (k == 2) ? m1.z : m1.w;
        p0[k] = mk ? __builtin_amdgcn_exp2f(e0) : 0.f;
        p1[k] = nk ? __builtin_amdgcn_exp2f(e1) : 0.f;
      }
      srow0 += (p0[0] + p0[1]) + (p0[2] + p0[3]);
      srow1 += (p1[0] + p1[1]) + (p1[2] + p1[3]);
      uint2 w0, w1;
      w0.x = pkrtz_u(p0[0], p0[1]);
      w0.y = pkrtz_u(p0[2], p0[3]);
      w1.x = pkrtz_u(p1[0], p1[1]);
      w1.y = pkrtz_u(p1[2], p1[3]);
      *(uint2*)&erow0[2 * g4] = w0;
      *(uint2*)&erow1[2 * g4] = w1;
    }
    s_part[jg][r0] = srow0;
    s_part[jg][r0 + 16] = srow1;
  }
  __syncthreads();

  // ---- phase 2': stage grT (fp16 v_perm) + row-sum reduce ----
  {
    const int fq = t & 7;    // f-quad
    const int jp0 = t >> 3;  // 0..63 (j-pair)
    const unsigned* gbase =
        (const unsigned*)(grh + (size_t)b * NN * HF + hh * FD) + 2 * fq;
#pragma unroll
    for (int s2 = 0; s2 < 4; ++s2) {
      const int jp = jp0 + 64 * s2;
      const uint2 A = *(const uint2*)(gbase + (size_t)(2 * jp) * 128);
      const uint2 Bv = *(const uint2*)(gbase + (size_t)(2 * jp + 1) * 128);
      // low16 = even j (matches pkrtz packing of p in e_s)
      ubuf[(4 * fq + 0) * GTS + jp] = __builtin_amdgcn_perm(Bv.x, A.x, 0x05040100u);
      ubuf[(4 * fq + 1) * GTS + jp] = __builtin_amdgcn_perm(Bv.x, A.x, 0x07060302u);
      ubuf[(4 * fq + 2) * GTS + jp] = __builtin_amdgcn_perm(Bv.y, A.y, 0x05040100u);
      ubuf[(4 * fq + 3) * GTS + jp] = __builtin_amdgcn_perm(Bv.y, A.y, 0x07060302u);
    }
    if (t < IT) {
      float s = 0.f;
#pragma unroll
      for (int c = 0; c < 32; ++c) s += s_part[c][t];
      inv_l[t] = 1.f / s;
    }
  }
  __syncthreads();

  // ---- phase 3: MFMA GEMM  C[32x32] = P . grT^T, waves 0-3, 1 tile/wave ----
  if (t < 256) {
    const int lane = t & 63;
    const int wv3 = t >> 6;          // 0..3
    const int Mt = wv3 & 1, Nt = wv3 >> 1;
    const int l16 = lane & 15, q = lane >> 4;
    const unsigned* arow = &e_s[Mt * 16 + l16][0];       // A[m][k] packed p
    const unsigned* brow = &ubuf[(Nt * 16 + l16) * GTS]; // B[k][n]=grT[n][k]
    v4f acc = {0.f, 0.f, 0.f, 0.f};
#pragma unroll
    for (int s = 0; s < 16; ++s) {
      U8 a; a.u4 = *(const uint4*)(arow + 16 * s + 4 * q);
      U8 bf; bf.u4 = *(const uint4*)(brow + 16 * s + 4 * q);
      acc = __builtin_amdgcn_mfma_f32_16x16x32_f16(a.h, bf.h, acc, 0, 0, 0);
    }
    // epilogue: D[row=q*4+r][col=l16], scale by inv_l, store
    float* op = out + (size_t)(b * NN + i0 + Mt * 16 + q * 4) * HF + hh * FD +
                Nt * 16 + l16;
#pragma unroll
    for (int r = 0; r < 4; ++r) {
      op[(size_t)r * HF] = acc[r] * inv_l[Mt * 16 + q * 4 + r];
    }
  }
}

// ---------------------------------------------------------------------------
extern "C" void kernel_launch(void* const* d_in, const int* in_sizes, int n_in,
                              void* d_out, int out_size, void* d_ws,
                              size_t ws_size, hipStream_t stream) {
  const float* h = (const float*)d_in[0];
  const int* adj = (const int*)d_in[1];
  const float* Wl = (const float*)d_in[2];
  const float* Wr = (const float*)d_in[3];
  const float* aw = (const float*)d_in[4];
  float* out = (float*)d_out;

  _Float16* glh = (_Float16*)d_ws;                                // 1 MB fp16
  _Float16* grh = (_Float16*)((char*)d_ws + (size_t)BB * NN * HF * 2);  // 1 MB

  dim3 gg(BB * NN / 8, 2, 1);
  gemm_dual<<<gg, 512, 0, stream>>>(h, Wl, Wr, glh, grh);

  dim3 ga(NH, NN / IT, BB);
  gat_attn<<<ga, 512, 0, stream>>>(glh, grh, adj, aw, out);
}

// Round 3
// 102.646 us; speedup vs baseline: 1.1752x; 1.1752x over previous
//
#include <hip/hip_runtime.h>
#include <math.h>

#define BB 4
#define NN 512
#define FIN 256
#define NH 8
#define FD 32
#define HF 256               // NH * FD
// leaky(x) = max(x, 0.21x) = CA*x + CB*|x|, pre-scaled by log2(e) so the
// softmax numerator is p = exp2(e) (saves the v_mul __expf emits).
#define CA 0.8728305f        // 0.605 * log2(e)
#define CB 0.5698645f        // 0.395 * log2(e)
#define IT 32                // i-tile rows; grid 512 = 2 blocks/CU
#define ESTR 268             // uints/e_s row: 1072B, 16B-aligned
#define GTS 260              // grT row stride in uints (16B-aligned)
// phase-1 wave holds 4 jg groups: XOR swizzle spreads their banks;
// permutation within 8-blocks so staging writes stay conflict-free
#define GLX(j) ((j) ^ (((j) >> 5) & 7))
#define ALX(j) ((j) + ((j) >> 5))
// gemm tiling
#define KT 64                // k-slab
#define HS 68                // padded LDS row stride (floats): 16B-aligned,
                             // 4-row step = 272 ≡ 16 (mod 32) -> worst 2-way

typedef _Float16 h2_t __attribute__((ext_vector_type(2)));
union H2U { unsigned u; h2_t h; };
typedef __fp16 v8h __attribute__((ext_vector_type(8)));  // MFMA a/b frag
typedef float v4f __attribute__((ext_vector_type(4)));   // MFMA acc
union U8 { uint4 u4; v8h h; };

__device__ __forceinline__ h2_t pkrtz(float a, float b) {
  auto r = __builtin_amdgcn_cvt_pkrtz(a, b);
  union { decltype(r) f; h2_t h; } u;
  u.f = r;
  return u.h;
}
__device__ __forceinline__ unsigned pkrtz_u(float a, float b) {
  H2U u; u.h = pkrtz(a, b);
  return u.u;
}

// x = g2 + q2 (v_pk_add_f16); |x| (v_and 0x7fff7fff); acc += u2.|x| (v_dot2)
__device__ __forceinline__ float acc2(unsigned g, h2_t q, h2_t u, float acc) {
  H2U v; v.u = g;
  h2_t s = v.h + q;
  H2U a; a.h = s; a.u &= 0x7fff7fffu;
  return __builtin_amdgcn_fdot2(a.h, u, acc, false);
}

// 32-feature score for one j from 4 uint4 (8 fp16 each)
__device__ __forceinline__ float score16(uint4 g0, uint4 g1, uint4 g2, uint4 g3,
                                         const h2_t* qh, const h2_t* uh,
                                         float init) {
  float e0 = init, e1 = 0.f;
  e0 = acc2(g0.x, qh[0], uh[0], e0);
  e1 = acc2(g0.y, qh[1], uh[1], e1);
  e0 = acc2(g0.z, qh[2], uh[2], e0);
  e1 = acc2(g0.w, qh[3], uh[3], e1);
  e0 = acc2(g1.x, qh[4], uh[4], e0);
  e1 = acc2(g1.y, qh[5], uh[5], e1);
  e0 = acc2(g1.z, qh[6], uh[6], e0);
  e1 = acc2(g1.w, qh[7], uh[7], e1);
  e0 = acc2(g2.x, qh[8], uh[8], e0);
  e1 = acc2(g2.y, qh[9], uh[9], e1);
  e0 = acc2(g2.z, qh[10], uh[10], e0);
  e1 = acc2(g2.w, qh[11], uh[11], e1);
  e0 = acc2(g3.x, qh[12], uh[12], e0);
  e1 = acc2(g3.y, qh[13], uh[13], e1);
  e0 = acc2(g3.z, qh[14], uh[14], e0);
  e1 = acc2(g3.w, qh[15], uh[15], e1);
  return e0 + e1;
}

// ---------------------------------------------------------------------------
// Kernel 1: dual GEMM g = h @ W, both outputs fp16.
// R15: LDS-tiled register-blocked fp32 GEMM. 64x64 output tile/block
// (grid 32 row-tiles x 8 col-strips over [Wl|Wr] = 256 blocks = 1/CU),
// K in 4 slabs of 64 staged to LDS (h 17KB + W 17KB, stride-68 padding),
// 4x4 micro-tile/thread: per k4, 8 ds_read_b128 feed 64 FMAs (FMA-bound,
// vs R10/R14's per-thread W-column L1-miss stream = 27-42us latency-bound).
// Next-slab global loads prefetched to regs before compute (T14 split).
// Per-output fmaf chain is the same ascending-k order as R10 with RNE
// fp16 converts -> bitwise-identical results.
// ---------------------------------------------------------------------------
__global__ __launch_bounds__(256) void gemm_dual(
    const float* __restrict__ h, const float* __restrict__ Wl,
    const float* __restrict__ Wr, _Float16* __restrict__ glh,
    _Float16* __restrict__ grh) {
  __shared__ __align__(16) float hs[KT * HS];   // [r 0..63][k 0..63] pad 68
  __shared__ __align__(16) float ws[KT * HS];   // [k 0..63][c 0..63] pad 68

  const int t = threadIdx.x;
  const int rt = blockIdx.x;          // row tile 0..31
  const int cs = blockIdx.y;          // col strip 0..7 over [Wl|Wr]
  const int row0 = rt * 64;
  const float* __restrict__ W = (cs < 4) ? Wl : Wr;
  const int c0 = (cs & 3) * 64;

  const int tc = t & 15;              // micro-tile col group (cols 4tc..+3)
  const int tr = t >> 4;              // micro-tile row group (rows 4tr..+3)
  const int sc = t & 15;              // staging quad-col
  const int sk = t >> 4;              // staging row base (rows sk+16i)

  float4 hr[4], wr_[4];               // staging regs (one slab ahead)
#pragma unroll
  for (int i = 0; i < 4; ++i) {
    hr[i] = *(const float4*)(h + (size_t)(row0 + sk + 16 * i) * FIN + 4 * sc);
    wr_[i] = *(const float4*)(W + (size_t)(sk + 16 * i) * HF + c0 + 4 * sc);
  }

  float acc[4][4];
#pragma unroll
  for (int i = 0; i < 4; ++i)
#pragma unroll
    for (int j = 0; j < 4; ++j) acc[i][j] = 0.f;

  for (int s = 0; s < 4; ++s) {
    if (s) __syncthreads();           // prior slab's reads complete
#pragma unroll
    for (int i = 0; i < 4; ++i) {
      *(float4*)&hs[(sk + 16 * i) * HS + 4 * sc] = hr[i];
      *(float4*)&ws[(sk + 16 * i) * HS + 4 * sc] = wr_[i];
    }
    __syncthreads();
    if (s < 3) {                      // prefetch next slab under compute
      const int k0 = KT * (s + 1);
#pragma unroll
      for (int i = 0; i < 4; ++i) {
        hr[i] = *(const float4*)(h + (size_t)(row0 + sk + 16 * i) * FIN +
                                 k0 + 4 * sc);
        wr_[i] = *(const float4*)(W + (size_t)(k0 + sk + 16 * i) * HF +
                                  c0 + 4 * sc);
      }
    }
#pragma unroll
    for (int k4 = 0; k4 < KT / 4; ++k4) {
      float4 hv[4], wv[4];
#pragma unroll
      for (int i = 0; i < 4; ++i)
        hv[i] = *(const float4*)&hs[(4 * tr + i) * HS + 4 * k4];
#pragma unroll
      for (int kk = 0; kk < 4; ++kk)
        wv[kk] = *(const float4*)&ws[(4 * k4 + kk) * HS + 4 * tc];
      // kk outer: each acc[i][j] accumulates ascending k (bitwise == R10)
#pragma unroll
      for (int kk = 0; kk < 4; ++kk) {
#pragma unroll
        for (int i = 0; i < 4; ++i) {
          const float hvk = (kk == 0) ? hv[i].x
                          : (kk == 1) ? hv[i].y
                          : (kk == 2) ? hv[i].z : hv[i].w;
          acc[i][0] = fmaf(hvk, wv[kk].x, acc[i][0]);
          acc[i][1] = fmaf(hvk, wv[kk].y, acc[i][1]);
          acc[i][2] = fmaf(hvk, wv[kk].z, acc[i][2]);
          acc[i][3] = fmaf(hvk, wv[kk].w, acc[i][3]);
        }
      }
    }
  }

  // epilogue: RNE fp16 converts (same as R10's scalar casts), 8B stores
  _Float16* gout = (cs < 4) ? glh : grh;
#pragma unroll
  for (int i = 0; i < 4; ++i) {
    const int row = row0 + 4 * tr + i;
    h2_t pa, pb;
    pa[0] = (_Float16)acc[i][0]; pa[1] = (_Float16)acc[i][1];
    pb[0] = (_Float16)acc[i][2]; pb[1] = (_Float16)acc[i][3];
    H2U ua, ub; ua.h = pa; ub.h = pb;
    uint2 o; o.x = ua.u; o.y = ub.u;
    *(uint2*)(gout + (size_t)row * HF + c0 + 4 * tc) = o;
  }
}

// ---------------------------------------------------------------------------
// Kernel 2: fused GATv2 attention. Block = (head hh, 32-row i-tile, batch b).
// R13 structure: 512-thread blocks (8 waves, 4/SIMD), 2 rows/thread sharing
// gl reads (r0 = t&15, jg = t>>4 spans 32 groups x 16 j). LDS 72.4 KB ->
// 2 blocks/CU; grid 512 blocks = exactly 2/CU, no tail.
// Softmax without max-pass (shift-invariant; e bounded ~|2|; masked p = 0
// exactly, matching ref's fp32 underflow); log2 domain: p = exp2(e).
// ---------------------------------------------------------------------------
__global__ __launch_bounds__(512, 4) void gat_attn(
    const _Float16* __restrict__ glh, const _Float16* __restrict__ grh,
    const int* __restrict__ adj, const float* __restrict__ aw,
    float* __restrict__ out) {
  __shared__ __align__(16) unsigned ubuf[32 * GTS];  // 33.3 KB gl4/grT union
  __shared__ __align__(16) unsigned e_s[IT][ESTR];   // 34.3 KB fp16 p
  __shared__ float Al_s[544];                        // 2.1 KB, ALX-skewed
  __shared__ float s_part[32][33];                   // 4.2 KB row-sum parts
  __shared__ float inv_l[IT];

  const int t = threadIdx.x;
  const int hh = blockIdx.x;
  const int i0 = blockIdx.y * IT;
  const int b = blockIdx.z;
  const int r0 = t & 15;   // phase-1 rows {r0, r0+16}
  const int jg = t >> 4;   // 0..31, 16 j each

  uint4* gl4 = (uint4*)ubuf;  // [k4*512 + GLX(j)], k-major

  const _Float16* glp = glh + (size_t)b * NN * HF + hh * FD;

  // ---- per-thread prep: aw -> wv/uh; q rows r0 & r0+16 -> qh/qh2 + a_r ----
  h2_t wv[16], uh[16], qh[16], qh2[16];
  float a_r0 = 0.f, a_r1 = 0.f;
  {
#pragma unroll
    for (int f4 = 0; f4 < 8; ++f4) {
      const float4 w4 = *(const float4*)(aw + 4 * f4);
      wv[2 * f4] = pkrtz(CA * w4.x, CA * w4.y);
      wv[2 * f4 + 1] = pkrtz(CA * w4.z, CA * w4.w);
      uh[2 * f4] = pkrtz(CB * w4.x, CB * w4.y);
      uh[2 * f4 + 1] = pkrtz(CB * w4.z, CB * w4.w);
    }
    const uint4* qa =
        (const uint4*)(grh + (size_t)(b * NN + i0 + r0) * HF + hh * FD);
    const uint4* qb =
        (const uint4*)(grh + (size_t)(b * NN + i0 + r0 + 16) * HF + hh * FD);
    const uint4 q0 = qa[0], q1 = qa[1], q2 = qa[2], q3 = qa[3];
    const uint4 p0 = qb[0], p1 = qb[1], p2 = qb[2], p3 = qb[3];
    H2U z;
    z.u = q0.x; qh[0] = z.h;  z.u = q0.y; qh[1] = z.h;
    z.u = q0.z; qh[2] = z.h;  z.u = q0.w; qh[3] = z.h;
    z.u = q1.x; qh[4] = z.h;  z.u = q1.y; qh[5] = z.h;
    z.u = q1.z; qh[6] = z.h;  z.u = q1.w; qh[7] = z.h;
    z.u = q2.x; qh[8] = z.h;  z.u = q2.y; qh[9] = z.h;
    z.u = q2.z; qh[10] = z.h; z.u = q2.w; qh[11] = z.h;
    z.u = q3.x; qh[12] = z.h; z.u = q3.y; qh[13] = z.h;
    z.u = q3.z; qh[14] = z.h; z.u = q3.w; qh[15] = z.h;
    z.u = p0.x; qh2[0] = z.h;  z.u = p0.y; qh2[1] = z.h;
    z.u = p0.z; qh2[2] = z.h;  z.u = p0.w; qh2[3] = z.h;
    z.u = p1.x; qh2[4] = z.h;  z.u = p1.y; qh2[5] = z.h;
    z.u = p1.z; qh2[6] = z.h;  z.u = p1.w; qh2[7] = z.h;
    z.u = p2.x; qh2[8] = z.h;  z.u = p2.y; qh2[9] = z.h;
    z.u = p2.z; qh2[10] = z.h; z.u = p2.w; qh2[11] = z.h;
    z.u = p3.x; qh2[12] = z.h; z.u = p3.y; qh2[13] = z.h;
    z.u = p3.z; qh2[14] = z.h; z.u = p3.w; qh2[15] = z.h;
#pragma unroll
    for (int f2 = 0; f2 < 16; ++f2) {
      a_r0 = __builtin_amdgcn_fdot2(qh[f2], wv[f2], a_r0, false);
      a_r1 = __builtin_amdgcn_fdot2(qh2[f2], wv[f2], a_r1, false);
    }
  }

  // ---- pre-pass: stage gl slice -> LDS (GLX-swizzled) + Al (ALX) ----
  {
    const int j = t;  // 512 threads, one j each
    const uint4* gp = (const uint4*)(glp + (size_t)j * HF);
    const uint4 g0 = gp[0], g1 = gp[1], g2 = gp[2], g3 = gp[3];
    const int jx = GLX(j);
    gl4[0 * NN + jx] = g0;
    gl4[1 * NN + jx] = g1;
    gl4[2 * NN + jx] = g2;
    gl4[3 * NN + jx] = g3;
    float s0 = 0.f, s1 = 0.f;
    H2U v;
#define ALD(gu, i)                                                  \
  v.u = gu.x; s0 = __builtin_amdgcn_fdot2(v.h, wv[i+0], s0, false); \
  v.u = gu.y; s1 = __builtin_amdgcn_fdot2(v.h, wv[i+1], s1, false); \
  v.u = gu.z; s0 = __builtin_amdgcn_fdot2(v.h, wv[i+2], s0, false); \
  v.u = gu.w; s1 = __builtin_amdgcn_fdot2(v.h, wv[i+3], s1, false);
    ALD(g0, 0) ALD(g1, 4) ALD(g2, 8) ALD(g3, 12)
#undef ALD
    Al_s[ALX(j)] = s0 + s1;
  }
  __syncthreads();

  // ---- phase 1: p = exp2(e) for 2 rows x 16 j; local row sums ----
  {
    unsigned* erow0 = &e_s[r0][jg * 8];
    unsigned* erow1 = &e_s[r0 + 16][jg * 8];
    const int* adjp0 = adj + (size_t)(i0 + r0) * NN + jg * 16;
    const int* adjp1 = adj + (size_t)(i0 + r0 + 16) * NN + jg * 16;
    float srow0 = 0.f, srow1 = 0.f;
#pragma unroll 2
    for (int g4 = 0; g4 < 4; ++g4) {
      const int4 m0 = ((const int4*)adjp0)[g4];
      const int4 m1 = ((const int4*)adjp1)[g4];
      float p0[4], p1[4];
#pragma unroll
      for (int k = 0; k < 4; ++k) {
        const int j = jg * 16 + 4 * g4 + k;
        const int jx = GLX(j);
        const uint4 g0 = gl4[0 * NN + jx], g1 = gl4[1 * NN + jx];
        const uint4 g2 = gl4[2 * NN + jx], g3 = gl4[3 * NN + jx];
        const float al = Al_s[ALX(j)];
        const float e0 = score16(g0, g1, g2, g3, qh, uh, al + a_r0);
        const float e1 = score16(g0, g1, g2, g3, qh2, uh, al + a_r1);
        const int mk = (k == 0) ? m0.x : (k == 1) ? m0.y : (k == 2) ? m0.z : m0.w;
        const int nk = (k == 0) ? m1.x : (k == 1) ? m1.y : (k == 2) ? m1.z : m1.w;
        p0[k] = mk ? __builtin_amdgcn_exp2f(e0) : 0.f;
        p1[k] = nk ? __builtin_amdgcn_exp2f(e1) : 0.f;
      }
      srow0 += (p0[0] + p0[1]) + (p0[2] + p0[3]);
      srow1 += (p1[0] + p1[1]) + (p1[2] + p1[3]);
      uint2 w0, w1;
      w0.x = pkrtz_u(p0[0], p0[1]);
      w0.y = pkrtz_u(p0[2], p0[3]);
      w1.x = pkrtz_u(p1[0], p1[1]);
      w1.y = pkrtz_u(p1[2], p1[3]);
      *(uint2*)&erow0[2 * g4] = w0;
      *(uint2*)&erow1[2 * g4] = w1;
    }
    s_part[jg][r0] = srow0;
    s_part[jg][r0 + 16] = srow1;
  }
  __syncthreads();

  // ---- phase 2': stage grT (fp16 v_perm) + row-sum reduce ----
  {
    const int fq = t & 7;    // f-quad
    const int jp0 = t >> 3;  // 0..63 (j-pair)
    const unsigned* gbase =
        (const unsigned*)(grh + (size_t)b * NN * HF + hh * FD) + 2 * fq;
#pragma unroll
    for (int s2 = 0; s2 < 4; ++s2) {
      const int jp = jp0 + 64 * s2;
      const uint2 A = *(const uint2*)(gbase + (size_t)(2 * jp) * 128);
      const uint2 Bv = *(const uint2*)(gbase + (size_t)(2 * jp + 1) * 128);
      // low16 = even j (matches pkrtz packing of p in e_s)
      ubuf[(4 * fq + 0) * GTS + jp] = __builtin_amdgcn_perm(Bv.x, A.x, 0x05040100u);
      ubuf[(4 * fq + 1) * GTS + jp] = __builtin_amdgcn_perm(Bv.x, A.x, 0x07060302u);
      ubuf[(4 * fq + 2) * GTS + jp] = __builtin_amdgcn_perm(Bv.y, A.y, 0x05040100u);
      ubuf[(4 * fq + 3) * GTS + jp] = __builtin_amdgcn_perm(Bv.y, A.y, 0x07060302u);
    }
    if (t < IT) {
      float s = 0.f;
#pragma unroll
      for (int c = 0; c < 32; ++c) s += s_part[c][t];
      inv_l[t] = 1.f / s;
    }
  }
  __syncthreads();

  // ---- phase 3: MFMA GEMM  C[32x32] = P . grT^T, waves 0-3, 1 tile/wave ----
  if (t < 256) {
    const int lane = t & 63;
    const int wv3 = t >> 6;          // 0..3
    const int Mt = wv3 & 1, Nt = wv3 >> 1;
    const int l16 = lane & 15, q = lane >> 4;
    const unsigned* arow = &e_s[Mt * 16 + l16][0];       // A[m][k] packed p
    const unsigned* brow = &ubuf[(Nt * 16 + l16) * GTS]; // B[k][n]=grT[n][k]
    v4f acc = {0.f, 0.f, 0.f, 0.f};
#pragma unroll
    for (int s = 0; s < 16; ++s) {
      U8 a; a.u4 = *(const uint4*)(arow + 16 * s + 4 * q);
      U8 bf; bf.u4 = *(const uint4*)(brow + 16 * s + 4 * q);
      acc = __builtin_amdgcn_mfma_f32_16x16x32_f16(a.h, bf.h, acc, 0, 0, 0);
    }
    // epilogue: D[row=q*4+r][col=l16], scale by inv_l, store
    float* op = out + (size_t)(b * NN + i0 + Mt * 16 + q * 4) * HF + hh * FD +
                Nt * 16 + l16;
#pragma unroll
    for (int r = 0; r < 4; ++r) {
      op[(size_t)r * HF] = acc[r] * inv_l[Mt * 16 + q * 4 + r];
    }
  }
}

// ---------------------------------------------------------------------------
extern "C" void kernel_launch(void* const* d_in, const int* in_sizes, int n_in,
                              void* d_out, int out_size, void* d_ws,
                              size_t ws_size, hipStream_t stream) {
  const float* h = (const float*)d_in[0];
  const int* adj = (const int*)d_in[1];
  const float* Wl = (const float*)d_in[2];
  const float* Wr = (const float*)d_in[3];
  const float* aw = (const float*)d_in[4];
  float* out = (float*)d_out;

  _Float16* glh = (_Float16*)d_ws;                                // 1 MB fp16
  _Float16* grh = (_Float16*)((char*)d_ws + (size_t)BB * NN * HF * 2);  // 1 MB

  dim3 gg(32, 8, 1);   // 64-row tiles x 8 col-strips = 256 blocks = 1/CU
  gemm_dual<<<gg, 256, 0, stream>>>(h, Wl, Wr, glh, grh);

  dim3 ga(NH, NN / IT, BB);
  gat_attn<<<ga, 512, 0, stream>>>(glh, grh, adj, aw, out);
}

// Round 4
// 90.176 us; speedup vs baseline: 1.3377x; 1.1383x over previous
//
#include <hip/hip_runtime.h>
#include <math.h>

#define BB 4
#define NN 512
#define FIN 256
#define NH 8
#define FD 32
#define HF 256               // NH * FD
// leaky(x) = max(x, 0.21x) = CA*x + CB*|x|, pre-scaled by log2(e) so the
// softmax numerator is p = exp2(e) (saves the v_mul __expf emits).
#define CA 0.8728305f        // 0.605 * log2(e)
#define CB 0.5698645f        // 0.395 * log2(e)
#define IT 32                // i-tile rows; grid 512 = 2 blocks/CU
#define ESTR 268             // uints/e_s row: 1072B, 16B-aligned
#define GTS 260              // grT row stride in uints (16B-aligned)
// phase-1 wave holds 4 jg groups: XOR swizzle spreads their banks;
// permutation within 8-blocks so staging writes stay conflict-free
#define GLX(j) ((j) ^ (((j) >> 5) & 7))
#define ALX(j) ((j) + ((j) >> 5))
// gemm: WT row stride in uints (k-pairs). 132 = 33 quads -> quarter-wave
// B-frag reads land 2-way (free) on banks.
#define WTS 132

typedef _Float16 h2_t __attribute__((ext_vector_type(2)));
union H2U { unsigned u; h2_t h; };
typedef __fp16 v8h __attribute__((ext_vector_type(8)));  // MFMA a/b frag
typedef float v4f __attribute__((ext_vector_type(4)));   // MFMA acc
union U8 { uint4 u4; v8h h; };

__device__ __forceinline__ h2_t pkrtz(float a, float b) {
  auto r = __builtin_amdgcn_cvt_pkrtz(a, b);
  union { decltype(r) f; h2_t h; } u;
  u.f = r;
  return u.h;
}
__device__ __forceinline__ unsigned pkrtz_u(float a, float b) {
  H2U u; u.h = pkrtz(a, b);
  return u.u;
}

// split a,b (fp32) into RNE-fp16 hi pair + 2048x-scaled fp16 residual pair.
// hi/lo packed low16 = a (even k). Exact: a - (float)ah is Sterbenz-exact,
// x2048 exact, residual fp16 rounding contributes <= 2^-22 rel.
__device__ __forceinline__ void split2(float a, float b,
                                       unsigned& uhi, unsigned& ulo) {
  const _Float16 ah = (_Float16)a, bh = (_Float16)b;
  h2_t hi; hi[0] = ah; hi[1] = bh;
  h2_t lo;
  lo[0] = (_Float16)((a - (float)ah) * 2048.f);
  lo[1] = (_Float16)((b - (float)bh) * 2048.f);
  H2U x, y; x.h = hi; y.h = lo;
  uhi = x.u; ulo = y.u;
}

// x = g2 + q2 (v_pk_add_f16); |x| (v_and 0x7fff7fff); acc += u2.|x| (v_dot2)
__device__ __forceinline__ float acc2(unsigned g, h2_t q, h2_t u, float acc) {
  H2U v; v.u = g;
  h2_t s = v.h + q;
  H2U a; a.h = s; a.u &= 0x7fff7fffu;
  return __builtin_amdgcn_fdot2(a.h, u, acc, false);
}

// 32-feature score for one j from 4 uint4 (8 fp16 each)
__device__ __forceinline__ float score16(uint4 g0, uint4 g1, uint4 g2, uint4 g3,
                                         const h2_t* qh, const h2_t* uh,
                                         float init) {
  float e0 = init, e1 = 0.f;
  e0 = acc2(g0.x, qh[0], uh[0], e0);
  e1 = acc2(g0.y, qh[1], uh[1], e1);
  e0 = acc2(g0.z, qh[2], uh[2], e0);
  e1 = acc2(g0.w, qh[3], uh[3], e1);
  e0 = acc2(g1.x, qh[4], uh[4], e0);
  e1 = acc2(g1.y, qh[5], uh[5], e1);
  e0 = acc2(g1.z, qh[6], uh[6], e0);
  e1 = acc2(g1.w, qh[7], uh[7], e1);
  e0 = acc2(g2.x, qh[8], uh[8], e0);
  e1 = acc2(g2.y, qh[9], uh[9], e1);
  e0 = acc2(g2.z, qh[10], uh[10], e0);
  e1 = acc2(g2.w, qh[11], uh[11], e1);
  e0 = acc2(g3.x, qh[12], uh[12], e0);
  e1 = acc2(g3.y, qh[13], uh[13], e1);
  e0 = acc2(g3.z, qh[14], uh[14], e0);
  e1 = acc2(g3.w, qh[15], uh[15], e1);
  return e0 + e1;
}

// ---------------------------------------------------------------------------
// Kernel 1: dual GEMM g = h @ W, both outputs fp16.
// R16: split-fp16 MFMA (fp32-accurate). Per block: 64x64 output tile
// (grid 32 x 8 over [Wl|Wr]); 4 waves, each one 16-row m-tile x 4 n-tiles.
// h A-frags preloaded from global into 64 VGPRs (converted+split per K-step
// in regs); W transposed+split to LDS fp16 (WTh=hi, WTl=2048*lo) during
// staging. g = hh*wh + (hh*wl + hl*wh)/2048; dropped hl*wl term is ~2^-22
// rel -> glh/grh bit-identical to the fp32 path except rare 1-ulp flips.
// Frag index math copied from the verified attn phase-3 MFMA.
// ---------------------------------------------------------------------------
__global__ __launch_bounds__(256) void gemm_dual(
    const float* __restrict__ h, const float* __restrict__ Wl,
    const float* __restrict__ Wr, _Float16* __restrict__ glh,
    _Float16* __restrict__ grh) {
  __shared__ __align__(16) unsigned WTh[64][WTS];  // 33 KB  W^T hi halves
  __shared__ __align__(16) unsigned WTl[64][WTS];  // 33 KB  W^T lo halves

  const int t = threadIdx.x;
  const int rt = blockIdx.x;          // row tile 0..31
  const int cs = blockIdx.y;          // col strip 0..7 over [Wl|Wr]
  const float* __restrict__ W = (cs < 4) ? Wl : Wr;
  const int c0 = (cs & 3) * 64;

  const int lane = t & 63;
  const int wv_ = t >> 6;             // wave 0..3 -> m-tile
  const int l16 = lane & 15;          // A-frag row / B-frag col
  const int q = lane >> 4;            // k-quad select
  const int row = rt * 64 + wv_ * 16 + l16;

  // ---- A preload: h[row][32s+8q .. +7] for s=0..7 (issued first; the
  // global latency hides under W staging below) ----
  const float* hp = h + (size_t)row * FIN;
  float4 ha[16];
#pragma unroll
  for (int s = 0; s < 8; ++s) {
    ha[2 * s]     = *(const float4*)(hp + 32 * s + 8 * q);
    ha[2 * s + 1] = *(const float4*)(hp + 32 * s + 8 * q + 4);
  }

  // ---- stage W^T split-fp16: thread (cq,kq) handles cols 4cq..+3,
  // k-pairs kq+16*it. Write bank pattern: quarter-wave has cq fixed,
  // kq 0..15 -> 16 consecutive banks, conflict-free. ----
  {
    const int cq = t >> 4;            // 0..15
    const int kq = t & 15;            // 0..15
#pragma unroll
    for (int it = 0; it < 8; ++it) {
      const int ku = kq + 16 * it;    // uint (k-pair) index 0..127
      const int k = 2 * ku;
      const float4 wa = *(const float4*)(W + (size_t)k * HF + c0 + 4 * cq);
      const float4 wb = *(const float4*)(W + (size_t)(k + 1) * HF + c0 + 4 * cq);
#pragma unroll
      for (int n = 0; n < 4; ++n) {
        const float a = (n == 0) ? wa.x : (n == 1) ? wa.y : (n == 2) ? wa.z : wa.w;
        const float b = (n == 0) ? wb.x : (n == 1) ? wb.y : (n == 2) ? wb.z : wb.w;
        unsigned uh_, ul_;
        split2(a, b, uh_, ul_);
        WTh[4 * cq + n][ku] = uh_;
        WTl[4 * cq + n][ku] = ul_;
      }
    }
  }
  __syncthreads();

  // ---- MFMA main loop: pure reg/LDS ----
  v4f accA[4], accB[4];
#pragma unroll
  for (int nt = 0; nt < 4; ++nt) {
    accA[nt] = (v4f){0.f, 0.f, 0.f, 0.f};
    accB[nt] = (v4f){0.f, 0.f, 0.f, 0.f};
  }
#pragma unroll
  for (int s = 0; s < 8; ++s) {
    U8 aH, aL;
    split2(ha[2 * s].x,     ha[2 * s].y,     aH.u4.x, aL.u4.x);
    split2(ha[2 * s].z,     ha[2 * s].w,     aH.u4.y, aL.u4.y);
    split2(ha[2 * s + 1].x, ha[2 * s + 1].y, aH.u4.z, aL.u4.z);
    split2(ha[2 * s + 1].z, ha[2 * s + 1].w, aH.u4.w, aL.u4.w);
#pragma unroll
    for (int nt = 0; nt < 4; ++nt) {
      const int col = nt * 16 + l16;
      U8 bH, bL;
      bH.u4 = *(const uint4*)&WTh[col][16 * s + 4 * q];
      bL.u4 = *(const uint4*)&WTl[col][16 * s + 4 * q];
      accA[nt] = __builtin_amdgcn_mfma_f32_16x16x32_f16(aH.h, bH.h, accA[nt], 0, 0, 0);
      accB[nt] = __builtin_amdgcn_mfma_f32_16x16x32_f16(aH.h, bL.h, accB[nt], 0, 0, 0);
      accB[nt] = __builtin_amdgcn_mfma_f32_16x16x32_f16(aL.h, bH.h, accB[nt], 0, 0, 0);
    }
  }

  // ---- epilogue: g = accA + accB/2048, RNE fp16, D[row=q*4+r][col=l16] ----
  _Float16* gout = (cs < 4) ? glh : grh;
  const int orow = rt * 64 + wv_ * 16 + q * 4;
#pragma unroll
  for (int nt = 0; nt < 4; ++nt) {
#pragma unroll
    for (int r = 0; r < 4; ++r) {
      const float g = accA[nt][r] + accB[nt][r] * (1.f / 2048.f);
      gout[(size_t)(orow + r) * HF + c0 + nt * 16 + l16] = (_Float16)g;
    }
  }
}

// ---------------------------------------------------------------------------
// Kernel 2: fused GATv2 attention. Block = (head hh, 32-row i-tile, batch b).
// R13 structure: 512-thread blocks (8 waves, 4/SIMD), 2 rows/thread sharing
// gl reads (r0 = t&15, jg = t>>4 spans 32 groups x 16 j). LDS 72.4 KB ->
// 2 blocks/CU; grid 512 blocks = exactly 2/CU, no tail.
// Softmax without max-pass (shift-invariant; e bounded ~|2|; masked p = 0
// exactly, matching ref's fp32 underflow); log2 domain: p = exp2(e).
// ---------------------------------------------------------------------------
__global__ __launch_bounds__(512, 4) void gat_attn(
    const _Float16* __restrict__ glh, const _Float16* __restrict__ grh,
    const int* __restrict__ adj, const float* __restrict__ aw,
    float* __restrict__ out) {
  __shared__ __align__(16) unsigned ubuf[32 * GTS];  // 33.3 KB gl4/grT union
  __shared__ __align__(16) unsigned e_s[IT][ESTR];   // 34.3 KB fp16 p
  __shared__ float Al_s[544];                        // 2.1 KB, ALX-skewed
  __shared__ float s_part[32][33];                   // 4.2 KB row-sum parts
  __shared__ float inv_l[IT];

  const int t = threadIdx.x;
  const int hh = blockIdx.x;
  const int i0 = blockIdx.y * IT;
  const int b = blockIdx.z;
  const int r0 = t & 15;   // phase-1 rows {r0, r0+16}
  const int jg = t >> 4;   // 0..31, 16 j each

  uint4* gl4 = (uint4*)ubuf;  // [k4*512 + GLX(j)], k-major

  const _Float16* glp = glh + (size_t)b * NN * HF + hh * FD;

  // ---- per-thread prep: aw -> wv/uh; q rows r0 & r0+16 -> qh/qh2 + a_r ----
  h2_t wv[16], uh[16], qh[16], qh2[16];
  float a_r0 = 0.f, a_r1 = 0.f;
  {
#pragma unroll
    for (int f4 = 0; f4 < 8; ++f4) {
      const float4 w4 = *(const float4*)(aw + 4 * f4);
      wv[2 * f4] = pkrtz(CA * w4.x, CA * w4.y);
      wv[2 * f4 + 1] = pkrtz(CA * w4.z, CA * w4.w);
      uh[2 * f4] = pkrtz(CB * w4.x, CB * w4.y);
      uh[2 * f4 + 1] = pkrtz(CB * w4.z, CB * w4.w);
    }
    const uint4* qa =
        (const uint4*)(grh + (size_t)(b * NN + i0 + r0) * HF + hh * FD);
    const uint4* qb =
        (const uint4*)(grh + (size_t)(b * NN + i0 + r0 + 16) * HF + hh * FD);
    const uint4 q0 = qa[0], q1 = qa[1], q2 = qa[2], q3 = qa[3];
    const uint4 p0 = qb[0], p1 = qb[1], p2 = qb[2], p3 = qb[3];
    H2U z;
    z.u = q0.x; qh[0] = z.h;  z.u = q0.y; qh[1] = z.h;
    z.u = q0.z; qh[2] = z.h;  z.u = q0.w; qh[3] = z.h;
    z.u = q1.x; qh[4] = z.h;  z.u = q1.y; qh[5] = z.h;
    z.u = q1.z; qh[6] = z.h;  z.u = q1.w; qh[7] = z.h;
    z.u = q2.x; qh[8] = z.h;  z.u = q2.y; qh[9] = z.h;
    z.u = q2.z; qh[10] = z.h; z.u = q2.w; qh[11] = z.h;
    z.u = q3.x; qh[12] = z.h; z.u = q3.y; qh[13] = z.h;
    z.u = q3.z; qh[14] = z.h; z.u = q3.w; qh[15] = z.h;
    z.u = p0.x; qh2[0] = z.h;  z.u = p0.y; qh2[1] = z.h;
    z.u = p0.z; qh2[2] = z.h;  z.u = p0.w; qh2[3] = z.h;
    z.u = p1.x; qh2[4] = z.h;  z.u = p1.y; qh2[5] = z.h;
    z.u = p1.z; qh2[6] = z.h;  z.u = p1.w; qh2[7] = z.h;
    z.u = p2.x; qh2[8] = z.h;  z.u = p2.y; qh2[9] = z.h;
    z.u = p2.z; qh2[10] = z.h; z.u = p2.w; qh2[11] = z.h;
    z.u = p3.x; qh2[12] = z.h; z.u = p3.y; qh2[13] = z.h;
    z.u = p3.z; qh2[14] = z.h; z.u = p3.w; qh2[15] = z.h;
#pragma unroll
    for (int f2 = 0; f2 < 16; ++f2) {
      a_r0 = __builtin_amdgcn_fdot2(qh[f2], wv[f2], a_r0, false);
      a_r1 = __builtin_amdgcn_fdot2(qh2[f2], wv[f2], a_r1, false);
    }
  }

  // ---- pre-pass: stage gl slice -> LDS (GLX-swizzled) + Al (ALX) ----
  {
    const int j = t;  // 512 threads, one j each
    const uint4* gp = (const uint4*)(glp + (size_t)j * HF);
    const uint4 g0 = gp[0], g1 = gp[1], g2 = gp[2], g3 = gp[3];
    const int jx = GLX(j);
    gl4[0 * NN + jx] = g0;
    gl4[1 * NN + jx] = g1;
    gl4[2 * NN + jx] = g2;
    gl4[3 * NN + jx] = g3;
    float s0 = 0.f, s1 = 0.f;
    H2U v;
#define ALD(gu, i)                                                  \
  v.u = gu.x; s0 = __builtin_amdgcn_fdot2(v.h, wv[i+0], s0, false); \
  v.u = gu.y; s1 = __builtin_amdgcn_fdot2(v.h, wv[i+1], s1, false); \
  v.u = gu.z; s0 = __builtin_amdgcn_fdot2(v.h, wv[i+2], s0, false); \
  v.u = gu.w; s1 = __builtin_amdgcn_fdot2(v.h, wv[i+3], s1, false);
    ALD(g0, 0) ALD(g1, 4) ALD(g2, 8) ALD(g3, 12)
#undef ALD
    Al_s[ALX(j)] = s0 + s1;
  }
  __syncthreads();

  // ---- phase 1: p = exp2(e) for 2 rows x 16 j; local row sums ----
  {
    unsigned* erow0 = &e_s[r0][jg * 8];
    unsigned* erow1 = &e_s[r0 + 16][jg * 8];
    const int* adjp0 = adj + (size_t)(i0 + r0) * NN + jg * 16;
    const int* adjp1 = adj + (size_t)(i0 + r0 + 16) * NN + jg * 16;
    float srow0 = 0.f, srow1 = 0.f;
#pragma unroll 2
    for (int g4 = 0; g4 < 4; ++g4) {
      const int4 m0 = ((const int4*)adjp0)[g4];
      const int4 m1 = ((const int4*)adjp1)[g4];
      float p0[4], p1[4];
#pragma unroll
      for (int k = 0; k < 4; ++k) {
        const int j = jg * 16 + 4 * g4 + k;
        const int jx = GLX(j);
        const uint4 g0 = gl4[0 * NN + jx], g1 = gl4[1 * NN + jx];
        const uint4 g2 = gl4[2 * NN + jx], g3 = gl4[3 * NN + jx];
        const float al = Al_s[ALX(j)];
        const float e0 = score16(g0, g1, g2, g3, qh, uh, al + a_r0);
        const float e1 = score16(g0, g1, g2, g3, qh2, uh, al + a_r1);
        const int mk = (k == 0) ? m0.x : (k == 1) ? m0.y : (k == 2) ? m0.z : m0.w;
        const int nk = (k == 0) ? m1.x : (k == 1) ? m1.y : (k == 2) ? m1.z : m1.w;
        p0[k] = mk ? __builtin_amdgcn_exp2f(e0) : 0.f;
        p1[k] = nk ? __builtin_amdgcn_exp2f(e1) : 0.f;
      }
      srow0 += (p0[0] + p0[1]) + (p0[2] + p0[3]);
      srow1 += (p1[0] + p1[1]) + (p1[2] + p1[3]);
      uint2 w0, w1;
      w0.x = pkrtz_u(p0[0], p0[1]);
      w0.y = pkrtz_u(p0[2], p0[3]);
      w1.x = pkrtz_u(p1[0], p1[1]);
      w1.y = pkrtz_u(p1[2], p1[3]);
      *(uint2*)&erow0[2 * g4] = w0;
      *(uint2*)&erow1[2 * g4] = w1;
    }
    s_part[jg][r0] = srow0;
    s_part[jg][r0 + 16] = srow1;
  }
  __syncthreads();

  // ---- phase 2': stage grT (fp16 v_perm) + row-sum reduce ----
  {
    const int fq = t & 7;    // f-quad
    const int jp0 = t >> 3;  // 0..63 (j-pair)
    const unsigned* gbase =
        (const unsigned*)(grh + (size_t)b * NN * HF + hh * FD) + 2 * fq;
#pragma unroll
    for (int s2 = 0; s2 < 4; ++s2) {
      const int jp = jp0 + 64 * s2;
      const uint2 A = *(const uint2*)(gbase + (size_t)(2 * jp) * 128);
      const uint2 Bv = *(const uint2*)(gbase + (size_t)(2 * jp + 1) * 128);
      // low16 = even j (matches pkrtz packing of p in e_s)
      ubuf[(4 * fq + 0) * GTS + jp] = __builtin_amdgcn_perm(Bv.x, A.x, 0x05040100u);
      ubuf[(4 * fq + 1) * GTS + jp] = __builtin_amdgcn_perm(Bv.x, A.x, 0x07060302u);
      ubuf[(4 * fq + 2) * GTS + jp] = __builtin_amdgcn_perm(Bv.y, A.y, 0x05040100u);
      ubuf[(4 * fq + 3) * GTS + jp] = __builtin_amdgcn_perm(Bv.y, A.y, 0x07060302u);
    }
    if (t < IT) {
      float s = 0.f;
#pragma unroll
      for (int c = 0; c < 32; ++c) s += s_part[c][t];
      inv_l[t] = 1.f / s;
    }
  }
  __syncthreads();

  // ---- phase 3: MFMA GEMM  C[32x32] = P . grT^T, waves 0-3, 1 tile/wave ----
  if (t < 256) {
    const int lane = t & 63;
    const int wv3 = t >> 6;          // 0..3
    const int Mt = wv3 & 1, Nt = wv3 >> 1;
    const int l16 = lane & 15, q = lane >> 4;
    const unsigned* arow = &e_s[Mt * 16 + l16][0];       // A[m][k] packed p
    const unsigned* brow = &ubuf[(Nt * 16 + l16) * GTS]; // B[k][n]=grT[n][k]
    v4f acc = {0.f, 0.f, 0.f, 0.f};
#pragma unroll
    for (int s = 0; s < 16; ++s) {
      U8 a; a.u4 = *(const uint4*)(arow + 16 * s + 4 * q);
      U8 bf; bf.u4 = *(const uint4*)(brow + 16 * s + 4 * q);
      acc = __builtin_amdgcn_mfma_f32_16x16x32_f16(a.h, bf.h, acc, 0, 0, 0);
    }
    // epilogue: D[row=q*4+r][col=l16], scale by inv_l, store
    float* op = out + (size_t)(b * NN + i0 + Mt * 16 + q * 4) * HF + hh * FD +
                Nt * 16 + l16;
#pragma unroll
    for (int r = 0; r < 4; ++r) {
      op[(size_t)r * HF] = acc[r] * inv_l[Mt * 16 + q * 4 + r];
    }
  }
}

// ---------------------------------------------------------------------------
extern "C" void kernel_launch(void* const* d_in, const int* in_sizes, int n_in,
                              void* d_out, int out_size, void* d_ws,
                              size_t ws_size, hipStream_t stream) {
  const float* h = (const float*)d_in[0];
  const int* adj = (const int*)d_in[1];
  const float* Wl = (const float*)d_in[2];
  const float* Wr = (const float*)d_in[3];
  const float* aw = (const float*)d_in[4];
  float* out = (float*)d_out;

  _Float16* glh = (_Float16*)d_ws;                                // 1 MB fp16
  _Float16* grh = (_Float16*)((char*)d_ws + (size_t)BB * NN * HF * 2);  // 1 MB

  dim3 gg(32, 8, 1);   // 64x64 tiles: 32 row-tiles x 8 col-strips
  gemm_dual<<<gg, 256, 0, stream>>>(h, Wl, Wr, glh, grh);

  dim3 ga(NH, NN / IT, BB);
  gat_attn<<<ga, 512, 0, stream>>>(glh, grh, adj, aw, out);
}